// Round 1
// baseline (663.358 us; speedup 1.0000x reference)
//
#include <hip/hip_runtime.h>

// MoE: HIDDEN=1024, FFN=4096, E=8, TOP_K=2, T=1024 tokens, all fp32 in/out.
// Strategy: route (top-2) -> gather per-expert token lists -> bf16 MFMA GEMMs.

typedef __bf16 bf16;
typedef __bf16 bf16x8 __attribute__((ext_vector_type(8)));
typedef float floatx4 __attribute__((ext_vector_type(4)));

#define T_TOK 1024
#define HID 1024
#define FFN 4096
#define NEXP 8

#define BM 128
#define BN 128
#define BK 32
#define PAD 8   // LDS row stride 40 bf16 = 80B (16B-aligned rows, conflict-light)

// ---------------- Router ----------------
// 1 wave per token. Computes 8 logits, top-2, softmax weights, compacts into
// per-expert lists via atomicAdd. entry = token*2 + slot.
__global__ void router_k(const float* __restrict__ x, const float* __restrict__ gw,
                         const float* __restrict__ gb, int* __restrict__ cnt,
                         int* __restrict__ elist, float* __restrict__ ewt) {
  int wave = threadIdx.x >> 6;
  int lane = threadIdx.x & 63;
  int t = blockIdx.x * 4 + wave;
  const float* xr = x + (size_t)t * HID;
  float xv[16];
#pragma unroll
  for (int j = 0; j < 16; j++) xv[j] = xr[lane + 64 * j];
  float logits[NEXP];
#pragma unroll
  for (int e = 0; e < NEXP; e++) {
    const float* g = gw + (size_t)e * HID;
    float s = 0.f;
#pragma unroll
    for (int j = 0; j < 16; j++) s += xv[j] * g[lane + 64 * j];
#pragma unroll
    for (int off = 32; off; off >>= 1) s += __shfl_xor(s, off, 64);
    logits[e] = s + gb[e];
  }
  // top-2 (first-index tie-break, matches lax.top_k)
  int i0 = 0; float l0 = logits[0];
#pragma unroll
  for (int e = 1; e < NEXP; e++) if (logits[e] > l0) { l0 = logits[e]; i0 = e; }
  int i1 = -1; float l1 = -3.0e38f;
#pragma unroll
  for (int e = 0; e < NEXP; e++) if (e != i0 && logits[e] > l1) { l1 = logits[e]; i1 = e; }
  if (lane == 0) {
    float w0 = 1.f / (1.f + expf(l1 - l0));   // l1 <= l0, stable
    float w1 = 1.f - w0;
    int p0 = atomicAdd(cnt + i0, 1);
    elist[i0 * T_TOK + p0] = t * 2 + 0; ewt[i0 * T_TOK + p0] = w0;
    int p1 = atomicAdd(cnt + i1, 1);
    elist[i1 * T_TOK + p1] = t * 2 + 1; ewt[i1 * T_TOK + p1] = w1;
  }
}

// ---------------- GEMM1: h = gelu(Xg @ w1[e] + b1[e]) ----------------
// A: gathered x rows (fp32 -> bf16 at staging). B: w1[e] (K=HID x N=FFN),
// transposed into LDS. Output: bf16 h[slot][FFN].
__global__ __launch_bounds__(256, 2)
void gemm1_k(const float* __restrict__ x, const float* __restrict__ w1,
             const float* __restrict__ b1, const int* __restrict__ cnt,
             const int* __restrict__ elist, bf16* __restrict__ hbuf) {
  int e = blockIdx.z;
  int c = cnt[e];
  int m0 = blockIdx.y * BM;
  if (m0 >= c) return;
  int n0 = blockIdx.x * BN;

  __shared__ bf16 As[BM][BK + PAD];
  __shared__ bf16 Bs[BN][BK + PAD];

  int tid = threadIdx.x;
  // A staging: thread -> (row, half of 32 cols)
  int arow = tid >> 1;
  int ahalf = tid & 1;
  int asrow = (m0 + arow < c) ? (m0 + arow) : m0;       // safe clamp (garbage rows never stored)
  int slot_a = elist[e * T_TOK + asrow];
  const float* aptr = x + (size_t)(slot_a >> 1) * HID + ahalf * 16;
  // B staging: thread -> (k row, 16-col chunk)
  int brow = tid >> 3;
  int bcol16 = (tid & 7) * 16;
  const float* bbase = w1 + ((size_t)e * HID * FFN) + n0 + bcol16;

  floatx4 acc[4][4] = {};
  int wave = tid >> 6, lane = tid & 63;
  int wm = (wave & 1) * 64;
  int wn = (wave >> 1) * 64;
  int fm = lane & 15;
  int quad = lane >> 4;

  for (int k0 = 0; k0 < HID; k0 += BK) {
    {
      const float* src = aptr + k0;
      float fv[16];
      *(float4*)(fv + 0)  = *(const float4*)(src + 0);
      *(float4*)(fv + 4)  = *(const float4*)(src + 4);
      *(float4*)(fv + 8)  = *(const float4*)(src + 8);
      *(float4*)(fv + 12) = *(const float4*)(src + 12);
      bf16 tv[16];
#pragma unroll
      for (int j = 0; j < 16; j++) tv[j] = (bf16)fv[j];
      *(bf16x8*)&As[arow][ahalf * 16 + 0] = *(bf16x8*)&tv[0];
      *(bf16x8*)&As[arow][ahalf * 16 + 8] = *(bf16x8*)&tv[8];
    }
    {
      const float* src = bbase + (size_t)(k0 + brow) * FFN;
      float gv[16];
      *(float4*)(gv + 0)  = *(const float4*)(src + 0);
      *(float4*)(gv + 4)  = *(const float4*)(src + 4);
      *(float4*)(gv + 8)  = *(const float4*)(src + 8);
      *(float4*)(gv + 12) = *(const float4*)(src + 12);
#pragma unroll
      for (int j = 0; j < 16; j++) Bs[bcol16 + j][brow] = (bf16)gv[j];
    }
    __syncthreads();
    bf16x8 af[4], bf[4];
#pragma unroll
    for (int i = 0; i < 4; i++) af[i] = *(const bf16x8*)&As[wm + i * 16 + fm][quad * 8];
#pragma unroll
    for (int j = 0; j < 4; j++) bf[j] = *(const bf16x8*)&Bs[wn + j * 16 + fm][quad * 8];
#pragma unroll
    for (int i = 0; i < 4; i++)
#pragma unroll
      for (int j = 0; j < 4; j++)
        acc[i][j] = __builtin_amdgcn_mfma_f32_16x16x32_bf16(af[i], bf[j], acc[i][j], 0, 0, 0);
    __syncthreads();
  }

  // Epilogue: bias + exact gelu, store bf16 h by slot
#pragma unroll
  for (int i = 0; i < 4; i++) {
    int rbase = m0 + wm + i * 16 + quad * 4;
#pragma unroll
    for (int j = 0; j < 4; j++) {
      int col = n0 + wn + j * 16 + fm;
      float bias = b1[e * FFN + col];
#pragma unroll
      for (int r = 0; r < 4; r++) {
        int row = rbase + r;
        if (row < c) {
          int slot = elist[e * T_TOK + row];
          float v = acc[i][j][r] + bias;
          float g = 0.5f * v * (1.f + erff(v * 0.70710678118654752f));
          hbuf[(size_t)slot * FFN + col] = (bf16)g;
        }
      }
    }
  }
}

// ---------------- GEMM2: y[slot] = wt * (h @ w2[e] + b2[e]) ----------------
__global__ __launch_bounds__(256, 2)
void gemm2_k(const bf16* __restrict__ hbuf, const float* __restrict__ w2,
             const float* __restrict__ b2, const int* __restrict__ cnt,
             const int* __restrict__ elist, const float* __restrict__ ewt,
             float* __restrict__ ybuf) {
  int e = blockIdx.z;
  int c = cnt[e];
  int m0 = blockIdx.y * BM;
  if (m0 >= c) return;
  int n0 = blockIdx.x * BN;

  __shared__ bf16 As[BM][BK + PAD];
  __shared__ bf16 Bs[BN][BK + PAD];

  int tid = threadIdx.x;
  int arow = tid >> 1;
  int ahalf = tid & 1;
  int asrow = (m0 + arow < c) ? (m0 + arow) : m0;
  int slot_a = elist[e * T_TOK + asrow];
  const float4* aptr = (const float4*)(hbuf + (size_t)slot_a * FFN);  // bf16 already
  int brow = tid >> 3;
  int bcol16 = (tid & 7) * 16;
  const float* bbase = w2 + ((size_t)e * FFN * HID) + n0 + bcol16;

  floatx4 acc[4][4] = {};
  int wave = tid >> 6, lane = tid & 63;
  int wm = (wave & 1) * 64;
  int wn = (wave >> 1) * 64;
  int fm = lane & 15;
  int quad = lane >> 4;

  for (int k0 = 0; k0 < FFN; k0 += BK) {
    {
      // 32 bf16 per row per iter; this thread copies 16 bf16 = 2 float4
      const float4* src = aptr + (k0 >> 2) / 2 + ahalf * 2;  // k0 bf16 -> k0/8 float4
      float4 v0 = src[0];
      float4 v1 = src[1];
      *(float4*)&As[arow][ahalf * 16 + 0] = v0;
      *(float4*)&As[arow][ahalf * 16 + 8] = v1;
    }
    {
      const float* src = bbase + (size_t)(k0 + brow) * HID;
      float gv[16];
      *(float4*)(gv + 0)  = *(const float4*)(src + 0);
      *(float4*)(gv + 4)  = *(const float4*)(src + 4);
      *(float4*)(gv + 8)  = *(const float4*)(src + 8);
      *(float4*)(gv + 12) = *(const float4*)(src + 12);
#pragma unroll
      for (int j = 0; j < 16; j++) Bs[bcol16 + j][brow] = (bf16)gv[j];
    }
    __syncthreads();
    bf16x8 af[4], bf[4];
#pragma unroll
    for (int i = 0; i < 4; i++) af[i] = *(const bf16x8*)&As[wm + i * 16 + fm][quad * 8];
#pragma unroll
    for (int j = 0; j < 4; j++) bf[j] = *(const bf16x8*)&Bs[wn + j * 16 + fm][quad * 8];
#pragma unroll
    for (int i = 0; i < 4; i++)
#pragma unroll
      for (int j = 0; j < 4; j++)
        acc[i][j] = __builtin_amdgcn_mfma_f32_16x16x32_bf16(af[i], bf[j], acc[i][j], 0, 0, 0);
    __syncthreads();
  }

#pragma unroll
  for (int i = 0; i < 4; i++) {
    int rbase = m0 + wm + i * 16 + quad * 4;
#pragma unroll
    for (int j = 0; j < 4; j++) {
      int col = n0 + wn + j * 16 + fm;
      float bias = b2[e * HID + col];
#pragma unroll
      for (int r = 0; r < 4; r++) {
        int row = rbase + r;
        if (row < c) {
          int slot = elist[e * T_TOK + row];
          float w = ewt[e * T_TOK + row];
          ybuf[(size_t)slot * HID + col] = w * (acc[i][j][r] + bias);
        }
      }
    }
  }
}

// ---------------- Combine: out[t] = y[t,0] + y[t,1] ----------------
__global__ void combine_k(const float* __restrict__ y, float* __restrict__ out) {
  int i = blockIdx.x * 256 + threadIdx.x;   // one float4 each
  int t = i >> 8;
  int h4 = (i & 255) * 4;
  const float* y0 = y + ((size_t)t * 2) * HID + h4;
  const float* y1 = y + ((size_t)t * 2 + 1) * HID + h4;
  float4 a = *(const float4*)y0;
  float4 b = *(const float4*)y1;
  float4 r;
  r.x = a.x + b.x; r.y = a.y + b.y; r.z = a.z + b.z; r.w = a.w + b.w;
  *(float4*)(out + (size_t)t * HID + h4) = r;
}

extern "C" void kernel_launch(void* const* d_in, const int* in_sizes, int n_in,
                              void* d_out, int out_size, void* d_ws, size_t ws_size,
                              hipStream_t stream) {
  const float* x  = (const float*)d_in[0];
  const float* gw = (const float*)d_in[1];
  const float* gb = (const float*)d_in[2];
  const float* w1 = (const float*)d_in[3];
  const float* b1 = (const float*)d_in[4];
  const float* w2 = (const float*)d_in[5];
  const float* b2 = (const float*)d_in[6];
  float* out = (float*)d_out;

  char* ws = (char*)d_ws;
  int*   cnt   = (int*)ws;                                   // 8 ints
  int*   elist = (int*)(ws + 64);                            // 8*1024 ints
  float* ewt   = (float*)(ws + 64 + 32768);                  // 8*1024 floats
  bf16*  hbuf  = (bf16*)(ws + 131072);                       // 2048*4096 bf16 = 16 MB
  float* ybuf  = (float*)(ws + 131072 + (size_t)2048 * 4096 * 2); // 2048*1024 fp32 = 8 MB

  hipMemsetAsync(cnt, 0, 32, stream);
  router_k<<<T_TOK / 4, 256, 0, stream>>>(x, gw, gb, cnt, elist, ewt);
  gemm1_k<<<dim3(FFN / BN, T_TOK / BM, NEXP), 256, 0, stream>>>(x, w1, b1, cnt, elist, hbuf);
  gemm2_k<<<dim3(HID / BN, T_TOK / BM, NEXP), 256, 0, stream>>>(hbuf, w2, b2, cnt, elist, ewt, ybuf);
  combine_k<<<(T_TOK * HID / 4) / 256, 256, 0, stream>>>(ybuf, out);
}

// Round 2
// 532.832 us; speedup vs baseline: 1.2450x; 1.2450x over previous
//
#include <hip/hip_runtime.h>

// MoE fp32: route top-2 -> gather -> bf16 MFMA GEMMs (m97-style K-loop).
// Pre-pass transposes weights to [n][k] bf16 so B-staging is a contiguous
// global_load_lds dwordx4 (no LDS transpose, no bank conflicts).

typedef __bf16 bf16;
typedef __bf16 bf16x8 __attribute__((ext_vector_type(8)));
typedef float floatx4 __attribute__((ext_vector_type(4)));

#define T_TOK 1024
#define HID 1024
#define FFN 4096
#define NEXP 8
#define BM 128
#define BN 128
#define BK 32

__device__ __forceinline__ void llds16(const void* g, void* l) {
  __builtin_amdgcn_global_load_lds((const __attribute__((address_space(1))) void*)g,
                                   (__attribute__((address_space(3))) void*)l, 16, 0, 0);
}

// ---------------- x -> bf16 ----------------
__global__ void xconv_k(const float* __restrict__ x, bf16* __restrict__ xb) {
  int i = blockIdx.x * 256 + threadIdx.x;  // 8 elems each
  float4 a = ((const float4*)x)[i * 2];
  float4 b = ((const float4*)x)[i * 2 + 1];
  bf16 t[8] = {(bf16)a.x, (bf16)a.y, (bf16)a.z, (bf16)a.w,
               (bf16)b.x, (bf16)b.y, (bf16)b.z, (bf16)b.w};
  *(bf16x8*)&xb[(size_t)i * 8] = *(bf16x8*)t;
}

// ---------------- transpose + convert: in (R,C) fp32 -> out (C,R) bf16 ----------------
// Thread owns out-row c, r-chunk of 64 -> its writes cover a full line.
__global__ void transconv_k(const float* __restrict__ in0, bf16* __restrict__ out0,
                            int R, int C) {
  const size_t eoff = (size_t)blockIdx.z * R * C;
  const float* in = in0 + eoff;
  bf16* out = out0 + eoff;
  int c = blockIdx.x * 256 + threadIdx.x;
  int r0 = blockIdx.y * 64;
#pragma unroll
  for (int jb = 0; jb < 8; jb++) {
    float v[8];
    bf16 b[8];
#pragma unroll
    for (int j = 0; j < 8; j++) v[j] = in[(size_t)(r0 + jb * 8 + j) * C + c];
#pragma unroll
    for (int j = 0; j < 8; j++) b[j] = (bf16)v[j];
    *(bf16x8*)&out[(size_t)c * R + r0 + jb * 8] = *(bf16x8*)b;
  }
}

// ---------------- Router ----------------
__global__ void router_k(const float* __restrict__ x, const float* __restrict__ gw,
                         const float* __restrict__ gb, int* __restrict__ cnt,
                         int* __restrict__ elist, float* __restrict__ ewt) {
  int wave = threadIdx.x >> 6;
  int lane = threadIdx.x & 63;
  int t = blockIdx.x * 4 + wave;
  const float* xr = x + (size_t)t * HID;
  float xv[16];
#pragma unroll
  for (int j = 0; j < 16; j++) xv[j] = xr[lane + 64 * j];
  float logits[NEXP];
#pragma unroll
  for (int e = 0; e < NEXP; e++) {
    const float* g = gw + (size_t)e * HID;
    float s = 0.f;
#pragma unroll
    for (int j = 0; j < 16; j++) s += xv[j] * g[lane + 64 * j];
#pragma unroll
    for (int off = 32; off; off >>= 1) s += __shfl_xor(s, off, 64);
    logits[e] = s + gb[e];
  }
  int i0 = 0; float l0 = logits[0];
#pragma unroll
  for (int e = 1; e < NEXP; e++) if (logits[e] > l0) { l0 = logits[e]; i0 = e; }
  int i1 = -1; float l1 = -3.0e38f;
#pragma unroll
  for (int e = 0; e < NEXP; e++) if (e != i0 && logits[e] > l1) { l1 = logits[e]; i1 = e; }
  if (lane == 0) {
    float w0 = 1.f / (1.f + expf(l1 - l0));
    float w1 = 1.f - w0;
    int p0 = atomicAdd(cnt + i0, 1);
    elist[i0 * T_TOK + p0] = t * 2 + 0; ewt[i0 * T_TOK + p0] = w0;
    int p1 = atomicAdd(cnt + i1, 1);
    elist[i1 * T_TOK + p1] = t * 2 + 1; ewt[i1 * T_TOK + p1] = w1;
  }
}

// ---------------- GEMM1: h = gelu(Xg @ w1 + b1), A/B bf16, global_load_lds ----------------
__global__ void gemm1_k(const bf16* __restrict__ xb, const bf16* __restrict__ w1t,
                        const float* __restrict__ b1, const int* __restrict__ cnt,
                        const int* __restrict__ elist, bf16* __restrict__ hbuf) {
  int e = blockIdx.z;
  int c = cnt[e];
  int m0 = blockIdx.y * BM;
  if (m0 >= c) return;
  int n0 = blockIdx.x * BN;

  __shared__ __align__(16) bf16 As[BM][BK];
  __shared__ __align__(16) bf16 Bs[BN][BK];

  int tid = threadIdx.x;
  int wv = tid >> 6, ln = tid & 63;
  int lrow = wv * 16 + (ln >> 2);
  int lk8 = (ln & 3) * 8;

  int ra0 = m0 + lrow;      if (ra0 >= c) ra0 = c - 1;
  int ra1 = m0 + lrow + 64; if (ra1 >= c) ra1 = c - 1;
  const bf16* ap0 = xb + (size_t)(elist[e * T_TOK + ra0] >> 1) * HID + lk8;
  const bf16* ap1 = xb + (size_t)(elist[e * T_TOK + ra1] >> 1) * HID + lk8;
  const bf16* w1e = w1t + (size_t)e * FFN * HID;
  const bf16* bp0 = w1e + (size_t)(n0 + lrow) * HID + lk8;
  const bf16* bp1 = bp0 + (size_t)64 * HID;
  bf16* ad0 = &As[wv * 16][0];
  bf16* ad1 = &As[64 + wv * 16][0];
  bf16* bd0 = &Bs[wv * 16][0];
  bf16* bd1 = &Bs[64 + wv * 16][0];

  floatx4 acc[4][4] = {};
  int fm = ln & 15, quad = ln >> 4;
  int wm = (wv & 1) * 64, wn = (wv >> 1) * 64;

  for (int k0 = 0; k0 < HID; k0 += BK) {
    llds16(ap0, ad0); llds16(ap1, ad1);
    llds16(bp0, bd0); llds16(bp1, bd1);
    ap0 += BK; ap1 += BK; bp0 += BK; bp1 += BK;
    __syncthreads();
    bf16x8 af[4], bfr[4];
#pragma unroll
    for (int i = 0; i < 4; i++) af[i] = *(const bf16x8*)&As[wm + i * 16 + fm][quad * 8];
#pragma unroll
    for (int j = 0; j < 4; j++) bfr[j] = *(const bf16x8*)&Bs[wn + j * 16 + fm][quad * 8];
#pragma unroll
    for (int i = 0; i < 4; i++)
#pragma unroll
      for (int j = 0; j < 4; j++)
        acc[i][j] = __builtin_amdgcn_mfma_f32_16x16x32_bf16(af[i], bfr[j], acc[i][j], 0, 0, 0);
    __syncthreads();
  }

  const float* b1e = b1 + (size_t)e * FFN;
#pragma unroll
  for (int i = 0; i < 4; i++) {
    int rb = m0 + wm + i * 16 + quad * 4;
#pragma unroll
    for (int j = 0; j < 4; j++) {
      int col = n0 + wn + j * 16 + fm;
      float bias = b1e[col];
#pragma unroll
      for (int r = 0; r < 4; r++) {
        int row = rb + r;
        if (row < c) {
          int slot = elist[e * T_TOK + row];
          float v = acc[i][j][r] + bias;
          float g = 0.5f * v * (1.f + erff(v * 0.70710678118654752f));
          hbuf[(size_t)slot * FFN + col] = (bf16)g;
        }
      }
    }
  }
}

// ---------------- GEMM2 split-K=4: part[ks][slot] = wt*(h @ w2 + b2?) ----------------
__global__ void gemm2_k(const bf16* __restrict__ hbuf, const bf16* __restrict__ w2t,
                        const float* __restrict__ b2, const int* __restrict__ cnt,
                        const int* __restrict__ elist, const float* __restrict__ ewt,
                        float* __restrict__ part) {
  int e = blockIdx.z & 7;
  int ks = blockIdx.z >> 3;
  int c = cnt[e];
  int m0 = blockIdx.y * BM;
  if (m0 >= c) return;
  int n0 = blockIdx.x * BN;
  int kbeg = ks * (FFN / 4);

  __shared__ __align__(16) bf16 As[BM][BK];
  __shared__ __align__(16) bf16 Bs[BN][BK];

  int tid = threadIdx.x;
  int wv = tid >> 6, ln = tid & 63;
  int lrow = wv * 16 + (ln >> 2);
  int lk8 = (ln & 3) * 8;

  int ra0 = m0 + lrow;      if (ra0 >= c) ra0 = c - 1;
  int ra1 = m0 + lrow + 64; if (ra1 >= c) ra1 = c - 1;
  const bf16* ap0 = hbuf + (size_t)elist[e * T_TOK + ra0] * FFN + kbeg + lk8;
  const bf16* ap1 = hbuf + (size_t)elist[e * T_TOK + ra1] * FFN + kbeg + lk8;
  const bf16* w2e = w2t + (size_t)e * HID * FFN;
  const bf16* bp0 = w2e + (size_t)(n0 + lrow) * FFN + kbeg + lk8;
  const bf16* bp1 = bp0 + (size_t)64 * FFN;
  bf16* ad0 = &As[wv * 16][0];
  bf16* ad1 = &As[64 + wv * 16][0];
  bf16* bd0 = &Bs[wv * 16][0];
  bf16* bd1 = &Bs[64 + wv * 16][0];

  floatx4 acc[4][4] = {};
  int fm = ln & 15, quad = ln >> 4;
  int wm = (wv & 1) * 64, wn = (wv >> 1) * 64;

  for (int it = 0; it < (FFN / 4) / BK; it++) {
    llds16(ap0, ad0); llds16(ap1, ad1);
    llds16(bp0, bd0); llds16(bp1, bd1);
    ap0 += BK; ap1 += BK; bp0 += BK; bp1 += BK;
    __syncthreads();
    bf16x8 af[4], bfr[4];
#pragma unroll
    for (int i = 0; i < 4; i++) af[i] = *(const bf16x8*)&As[wm + i * 16 + fm][quad * 8];
#pragma unroll
    for (int j = 0; j < 4; j++) bfr[j] = *(const bf16x8*)&Bs[wn + j * 16 + fm][quad * 8];
#pragma unroll
    for (int i = 0; i < 4; i++)
#pragma unroll
      for (int j = 0; j < 4; j++)
        acc[i][j] = __builtin_amdgcn_mfma_f32_16x16x32_bf16(af[i], bfr[j], acc[i][j], 0, 0, 0);
    __syncthreads();
  }

  const float* b2e = b2 + (size_t)e * HID;
#pragma unroll
  for (int i = 0; i < 4; i++) {
    int rb = m0 + wm + i * 16 + quad * 4;
#pragma unroll
    for (int j = 0; j < 4; j++) {
      int col = n0 + wn + j * 16 + fm;
      float bias = (ks == 0) ? b2e[col] : 0.f;
#pragma unroll
      for (int r = 0; r < 4; r++) {
        int row = rb + r;
        if (row < c) {
          int slot = elist[e * T_TOK + row];
          float w = ewt[e * T_TOK + row];
          part[((size_t)ks * (2 * T_TOK) + slot) * HID + col] = w * (acc[i][j][r] + bias);
        }
      }
    }
  }
}

// ---------------- Combine: out[t] = sum over 4 ks x 2 slots ----------------
__global__ void combine_k(const float* __restrict__ part, float* __restrict__ out) {
  int i = blockIdx.x * 256 + threadIdx.x;
  int t = i >> 8;
  int h4 = (i & 255) * 4;
  float4 s = {0.f, 0.f, 0.f, 0.f};
#pragma unroll
  for (int ks = 0; ks < 4; ks++)
#pragma unroll
    for (int sl = 0; sl < 2; sl++) {
      float4 v = *(const float4*)&part[((size_t)ks * (2 * T_TOK) + t * 2 + sl) * HID + h4];
      s.x += v.x; s.y += v.y; s.z += v.z; s.w += v.w;
    }
  *(float4*)&out[(size_t)t * HID + h4] = s;
}

extern "C" void kernel_launch(void* const* d_in, const int* in_sizes, int n_in,
                              void* d_out, int out_size, void* d_ws, size_t ws_size,
                              hipStream_t stream) {
  const float* x  = (const float*)d_in[0];
  const float* gw = (const float*)d_in[1];
  const float* gb = (const float*)d_in[2];
  const float* w1 = (const float*)d_in[3];
  const float* b1 = (const float*)d_in[4];
  const float* w2 = (const float*)d_in[5];
  const float* b2 = (const float*)d_in[6];
  float* out = (float*)d_out;

  char* ws = (char*)d_ws;
  int*   cnt   = (int*)ws;                                    // 32 B
  int*   elist = (int*)(ws + 1024);                           // 32 KB
  float* ewt   = (float*)(ws + 1024 + 32768);                 // 32 KB
  bf16*  xb    = (bf16*)(ws + (1 << 16));                     // 2 MB
  bf16*  wt    = (bf16*)(ws + ((size_t)4 << 20));             // 67.1 MB (shared w1t/w2t)
  size_t hoff  = ((size_t)4 << 20) + (size_t)NEXP * FFN * HID * 2;
  bf16*  hbuf  = (bf16*)(ws + hoff);                          // 16.8 MB
  float* part  = (float*)(ws + hoff + (size_t)(2 * T_TOK) * FFN * 2);  // 33.6 MB

  hipMemsetAsync(cnt, 0, 32, stream);
  xconv_k<<<512, 256, 0, stream>>>(x, xb);
  router_k<<<T_TOK / 4, 256, 0, stream>>>(x, gw, gb, cnt, elist, ewt);
  // w1 (H,F) -> wt (F,H) per expert
  transconv_k<<<dim3(FFN / 256, HID / 64, NEXP), 256, 0, stream>>>(w1, wt, HID, FFN);
  gemm1_k<<<dim3(FFN / BN, 8, NEXP), 256, 0, stream>>>(xb, wt, b1, cnt, elist, hbuf);
  // w2 (F,H) -> wt (H,F) per expert (reuses buffer; stream-ordered after gemm1)
  transconv_k<<<dim3(HID / 256, FFN / 64, NEXP), 256, 0, stream>>>(w2, wt, FFN, HID);
  gemm2_k<<<dim3(HID / BN, 8, NEXP * 4), 256, 0, stream>>>(hbuf, wt, b2, cnt, elist, ewt, part);
  combine_k<<<(T_TOK * HID / 4) / 256, 256, 0, stream>>>(part, out);
}

// Round 3
// 436.248 us; speedup vs baseline: 1.5206x; 1.2214x over previous
//
#include <hip/hip_runtime.h>

// MoE fp32: route top-2 -> gather -> bf16 MFMA GEMMs.
// No weight pre-transpose: GEMMs read fp32 weights in natural (k,n) layout,
// convert+transpose during LDS staging through VGPRs (conflict-free padded
// rows), with register-level prefetch of tile t+1 across the MFMAs of tile t.

typedef __bf16 bf16;
typedef __bf16 bf16x8 __attribute__((ext_vector_type(8)));
typedef float floatx4 __attribute__((ext_vector_type(4)));

#define T_TOK 1024
#define HID 1024
#define FFN 4096
#define NEXP 8
#define BM 128
#define BN 128
#define BK 32
#define LP 36   // LDS row stride (bf16) = 18 dwords: conflict-free b128 r/w

// ---------------- x -> bf16 ----------------
__global__ void xconv_k(const float* __restrict__ x, bf16* __restrict__ xb) {
  int i = blockIdx.x * 256 + threadIdx.x;  // 8 elems each
  float4 a = ((const float4*)x)[i * 2];
  float4 b = ((const float4*)x)[i * 2 + 1];
  bf16 t[8] = {(bf16)a.x, (bf16)a.y, (bf16)a.z, (bf16)a.w,
               (bf16)b.x, (bf16)b.y, (bf16)b.z, (bf16)b.w};
  *(bf16x8*)&xb[(size_t)i * 8] = *(bf16x8*)t;
}

// ---------------- Router ----------------
__global__ void router_k(const float* __restrict__ x, const float* __restrict__ gw,
                         const float* __restrict__ gb, int* __restrict__ cnt,
                         int* __restrict__ elist, float* __restrict__ ewt) {
  int wave = threadIdx.x >> 6;
  int lane = threadIdx.x & 63;
  int t = blockIdx.x * 4 + wave;
  const float* xr = x + (size_t)t * HID;
  float xv[16];
#pragma unroll
  for (int j = 0; j < 16; j++) xv[j] = xr[lane + 64 * j];
  float logits[NEXP];
#pragma unroll
  for (int e = 0; e < NEXP; e++) {
    const float* g = gw + (size_t)e * HID;
    float s = 0.f;
#pragma unroll
    for (int j = 0; j < 16; j++) s += xv[j] * g[lane + 64 * j];
#pragma unroll
    for (int off = 32; off; off >>= 1) s += __shfl_xor(s, off, 64);
    logits[e] = s + gb[e];
  }
  int i0 = 0; float l0 = logits[0];
#pragma unroll
  for (int e = 1; e < NEXP; e++) if (logits[e] > l0) { l0 = logits[e]; i0 = e; }
  int i1 = -1; float l1 = -3.0e38f;
#pragma unroll
  for (int e = 0; e < NEXP; e++) if (e != i0 && logits[e] > l1) { l1 = logits[e]; i1 = e; }
  if (lane == 0) {
    float w0 = 1.f / (1.f + expf(l1 - l0));
    float w1 = 1.f - w0;
    int p0 = atomicAdd(cnt + i0, 1);
    elist[i0 * T_TOK + p0] = t * 2 + 0; ewt[i0 * T_TOK + p0] = w0;
    int p1 = atomicAdd(cnt + i1, 1);
    elist[i1 * T_TOK + p1] = t * 2 + 1; ewt[i1 * T_TOK + p1] = w1;
  }
}

// ---------------- GEMM1: h = gelu(Xg @ w1 + b1) ----------------
// A: gathered xb rows (bf16). B: w1[e] fp32 (k=H rows, n=F cols) -> LDS (n,k) bf16.
__global__ __launch_bounds__(256)
void gemm1_k(const bf16* __restrict__ xb, const float* __restrict__ w1,
             const float* __restrict__ b1, const int* __restrict__ cnt,
             const int* __restrict__ elist, bf16* __restrict__ hbuf) {
  int e = blockIdx.z;
  int c = cnt[e];
  int m0 = blockIdx.y * BM;
  if (m0 >= c) return;
  int n0 = blockIdx.x * BN;

  __shared__ __align__(16) bf16 As[BM][LP];
  __shared__ __align__(16) bf16 Bs[BN][LP];

  int tid = threadIdx.x;
  int ar = tid >> 1;
  int ac = (tid & 1) * 16;
  int ra = m0 + ar; if (ra >= c) ra = c - 1;
  const bf16* aptr = xb + (size_t)(elist[e * T_TOK + ra] >> 1) * HID + ac;
  int bn = tid & 127;
  int bk = (tid >> 7) * 16;
  const float* bptr = w1 + (size_t)e * HID * FFN + (size_t)bk * FFN + n0 + bn;

  uint4 a0, a1;
  float bfl[16];
  a0 = *(const uint4*)(aptr);
  a1 = *(const uint4*)(aptr + 8);
#pragma unroll
  for (int j = 0; j < 16; j++) bfl[j] = bptr[(size_t)j * FFN];

  floatx4 acc[4][4] = {};
  int ln = tid & 63, wv = tid >> 6;
  int fm = ln & 15, quad = ln >> 4;
  int wm = (wv & 1) * 64, wn = (wv >> 1) * 64;

  for (int t = 0; t < HID / BK; t++) {
    bf16 bb[16];
#pragma unroll
    for (int j = 0; j < 16; j++) bb[j] = (bf16)bfl[j];
    uint4 wa0 = a0, wa1 = a1;
    __syncthreads();                       // frag reads of tile t-1 done
    *(uint4*)&As[ar][ac]      = wa0;
    *(uint4*)&As[ar][ac + 8]  = wa1;
    *(bf16x8*)&Bs[bn][bk]     = *(bf16x8*)&bb[0];
    *(bf16x8*)&Bs[bn][bk + 8] = *(bf16x8*)&bb[8];
    if (t + 1 < HID / BK) {                // prefetch t+1: in flight across MFMAs
      aptr += BK;
      a0 = *(const uint4*)(aptr);
      a1 = *(const uint4*)(aptr + 8);
      bptr += (size_t)BK * FFN;
#pragma unroll
      for (int j = 0; j < 16; j++) bfl[j] = bptr[(size_t)j * FFN];
    }
    __syncthreads();                       // writes visible
    bf16x8 af[4], bfr[4];
#pragma unroll
    for (int i = 0; i < 4; i++) af[i] = *(const bf16x8*)&As[wm + i * 16 + fm][quad * 8];
#pragma unroll
    for (int j = 0; j < 4; j++) bfr[j] = *(const bf16x8*)&Bs[wn + j * 16 + fm][quad * 8];
#pragma unroll
    for (int i = 0; i < 4; i++)
#pragma unroll
      for (int j = 0; j < 4; j++)
        acc[i][j] = __builtin_amdgcn_mfma_f32_16x16x32_bf16(af[i], bfr[j], acc[i][j], 0, 0, 0);
  }

  const float* b1e = b1 + (size_t)e * FFN;
#pragma unroll
  for (int i = 0; i < 4; i++) {
    int rb = m0 + wm + i * 16 + quad * 4;
#pragma unroll
    for (int j = 0; j < 4; j++) {
      int col = n0 + wn + j * 16 + fm;
      float bias = b1e[col];
#pragma unroll
      for (int r = 0; r < 4; r++) {
        int row = rb + r;
        if (row < c) {
          int slot = elist[e * T_TOK + row];
          float v = acc[i][j][r] + bias;
          float g = 0.5f * v * (1.f + erff(v * 0.70710678118654752f));
          hbuf[(size_t)slot * FFN + col] = (bf16)g;
        }
      }
    }
  }
}

// ---------------- GEMM2 split-K=4: part[ks][slot] = wt*(h @ w2 + b2?) ----------------
__global__ __launch_bounds__(256)
void gemm2_k(const bf16* __restrict__ hbuf, const float* __restrict__ w2,
             const float* __restrict__ b2, const int* __restrict__ cnt,
             const int* __restrict__ elist, const float* __restrict__ ewt,
             float* __restrict__ part) {
  int e = blockIdx.z & 7;
  int ks = blockIdx.z >> 3;
  int c = cnt[e];
  int m0 = blockIdx.y * BM;
  if (m0 >= c) return;
  int n0 = blockIdx.x * BN;
  int kbeg = ks * (FFN / 4);

  __shared__ __align__(16) bf16 As[BM][LP];
  __shared__ __align__(16) bf16 Bs[BN][LP];

  int tid = threadIdx.x;
  int ar = tid >> 1;
  int ac = (tid & 1) * 16;
  int ra = m0 + ar; if (ra >= c) ra = c - 1;
  const bf16* aptr = hbuf + (size_t)elist[e * T_TOK + ra] * FFN + kbeg + ac;
  int bn = tid & 127;
  int bk = (tid >> 7) * 16;
  const float* bptr = w2 + (size_t)e * FFN * HID + (size_t)(kbeg + bk) * HID + n0 + bn;

  uint4 a0, a1;
  float bfl[16];
  a0 = *(const uint4*)(aptr);
  a1 = *(const uint4*)(aptr + 8);
#pragma unroll
  for (int j = 0; j < 16; j++) bfl[j] = bptr[(size_t)j * HID];

  floatx4 acc[4][4] = {};
  int ln = tid & 63, wv = tid >> 6;
  int fm = ln & 15, quad = ln >> 4;
  int wm = (wv & 1) * 64, wn = (wv >> 1) * 64;

  const int NT = (FFN / 4) / BK;
  for (int t = 0; t < NT; t++) {
    bf16 bb[16];
#pragma unroll
    for (int j = 0; j < 16; j++) bb[j] = (bf16)bfl[j];
    uint4 wa0 = a0, wa1 = a1;
    __syncthreads();
    *(uint4*)&As[ar][ac]      = wa0;
    *(uint4*)&As[ar][ac + 8]  = wa1;
    *(bf16x8*)&Bs[bn][bk]     = *(bf16x8*)&bb[0];
    *(bf16x8*)&Bs[bn][bk + 8] = *(bf16x8*)&bb[8];
    if (t + 1 < NT) {
      aptr += BK;
      a0 = *(const uint4*)(aptr);
      a1 = *(const uint4*)(aptr + 8);
      bptr += (size_t)BK * HID;
#pragma unroll
      for (int j = 0; j < 16; j++) bfl[j] = bptr[(size_t)j * HID];
    }
    __syncthreads();
    bf16x8 af[4], bfr[4];
#pragma unroll
    for (int i = 0; i < 4; i++) af[i] = *(const bf16x8*)&As[wm + i * 16 + fm][quad * 8];
#pragma unroll
    for (int j = 0; j < 4; j++) bfr[j] = *(const bf16x8*)&Bs[wn + j * 16 + fm][quad * 8];
#pragma unroll
    for (int i = 0; i < 4; i++)
#pragma unroll
      for (int j = 0; j < 4; j++)
        acc[i][j] = __builtin_amdgcn_mfma_f32_16x16x32_bf16(af[i], bfr[j], acc[i][j], 0, 0, 0);
  }

  const float* b2e = b2 + (size_t)e * HID;
#pragma unroll
  for (int i = 0; i < 4; i++) {
    int rb = m0 + wm + i * 16 + quad * 4;
#pragma unroll
    for (int j = 0; j < 4; j++) {
      int col = n0 + wn + j * 16 + fm;
      float bias = (ks == 0) ? b2e[col] : 0.f;
#pragma unroll
      for (int r = 0; r < 4; r++) {
        int row = rb + r;
        if (row < c) {
          int slot = elist[e * T_TOK + row];
          float w = ewt[e * T_TOK + row];
          part[((size_t)ks * (2 * T_TOK) + slot) * HID + col] = w * (acc[i][j][r] + bias);
        }
      }
    }
  }
}

// ---------------- Combine ----------------
__global__ void combine_k(const float* __restrict__ part, float* __restrict__ out) {
  int i = blockIdx.x * 256 + threadIdx.x;
  int t = i >> 8;
  int h4 = (i & 255) * 4;
  float4 s = {0.f, 0.f, 0.f, 0.f};
#pragma unroll
  for (int ks = 0; ks < 4; ks++)
#pragma unroll
    for (int sl = 0; sl < 2; sl++) {
      float4 v = *(const float4*)&part[((size_t)ks * (2 * T_TOK) + t * 2 + sl) * HID + h4];
      s.x += v.x; s.y += v.y; s.z += v.z; s.w += v.w;
    }
  *(float4*)&out[(size_t)t * HID + h4] = s;
}

extern "C" void kernel_launch(void* const* d_in, const int* in_sizes, int n_in,
                              void* d_out, int out_size, void* d_ws, size_t ws_size,
                              hipStream_t stream) {
  const float* x  = (const float*)d_in[0];
  const float* gw = (const float*)d_in[1];
  const float* gb = (const float*)d_in[2];
  const float* w1 = (const float*)d_in[3];
  const float* b1 = (const float*)d_in[4];
  const float* w2 = (const float*)d_in[5];
  const float* b2 = (const float*)d_in[6];
  float* out = (float*)d_out;

  char* ws = (char*)d_ws;
  int*   cnt   = (int*)ws;                                   // 32 B
  int*   elist = (int*)(ws + 1024);                          // 32 KB
  float* ewt   = (float*)(ws + 1024 + 32768);                // 32 KB
  bf16*  xb    = (bf16*)(ws + (1 << 16));                    // 2 MB
  bf16*  hbuf  = (bf16*)(ws + ((size_t)4 << 20));            // 16.8 MB
  float* part  = (float*)(ws + ((size_t)24 << 20));          // 33.6 MB

  hipMemsetAsync(cnt, 0, 32, stream);
  xconv_k<<<512, 256, 0, stream>>>(x, xb);
  router_k<<<T_TOK / 4, 256, 0, stream>>>(x, gw, gb, cnt, elist, ewt);
  gemm1_k<<<dim3(FFN / BN, 8, NEXP), 256, 0, stream>>>(xb, w1, b1, cnt, elist, hbuf);
  gemm2_k<<<dim3(HID / BN, 8, NEXP * 4), 256, 0, stream>>>(hbuf, w2, b2, cnt, elist, ewt, part);
  combine_k<<<(T_TOK * HID / 4) / 256, 256, 0, stream>>>(part, out);
}